// Round 1
// baseline (835.728 us; speedup 1.0000x reference)
//
#include <hip/hip_runtime.h>
#include <hip/hip_bf16.h>

#define N_NODES 6144
#define NQ_ 3072
#define D 128
#define H 4
#define C 32
#define F_IN 10
#define L_LAYERS 4
#define E_EDGES 393216
#define E_TOT (E_EDGES + N_NODES)

// ---------- helpers ----------
__device__ __forceinline__ float red128_sum(float v, float* tmp2, int tid) {
#pragma unroll
  for (int m = 1; m < 64; m <<= 1) v += __shfl_xor(v, m, 64);
  __syncthreads();                 // protect tmp2 reuse across calls
  if ((tid & 63) == 0) tmp2[tid >> 6] = v;
  __syncthreads();
  return tmp2[0] + tmp2[1];
}

// ---------- CSR build ----------
__global__ void k_zero(int* cnt, int* cur, float* pooled) {
  int i = blockIdx.x * blockDim.x + threadIdx.x;
  if (i < N_NODES) { cnt[i] = 0; cur[i] = 0; }
  if (i < D) pooled[i] = 0.f;
}

__global__ void k_hist(const int* __restrict__ dst, int* __restrict__ cnt) {
  for (int i = blockIdx.x * blockDim.x + threadIdx.x; i < E_EDGES; i += gridDim.x * blockDim.x)
    atomicAdd(&cnt[dst[i]], 1);
}

__global__ void k_scan(const int* __restrict__ cnt, int* __restrict__ indptr) {
  __shared__ int ps[256];
  int tid = threadIdx.x;
  const int CH = N_NODES / 256;  // 24
  int base = tid * CH;
  int loc[CH];
  int s = 0;
#pragma unroll
  for (int i = 0; i < CH; i++) { loc[i] = cnt[base + i] + 1; s += loc[i]; }  // +1 self loop
  ps[tid] = s;
  __syncthreads();
  for (int off = 1; off < 256; off <<= 1) {
    int v = (tid >= off) ? ps[tid - off] : 0;
    __syncthreads();
    ps[tid] += v;
    __syncthreads();
  }
  int run = (tid == 0) ? 0 : ps[tid - 1];
#pragma unroll
  for (int i = 0; i < CH; i++) { indptr[base + i] = run; run += loc[i]; }
  if (tid == 255) indptr[N_NODES] = run;
}

__global__ void k_scatter(const int* __restrict__ src, const int* __restrict__ dst,
                          const int* __restrict__ indptr, int* __restrict__ cur,
                          int* __restrict__ sorted) {
  for (int i = blockIdx.x * blockDim.x + threadIdx.x; i < E_TOT; i += gridDim.x * blockDim.x) {
    if (i < E_EDGES) {
      int d = dst[i];
      int p = atomicAdd(&cur[d], 1);
      sorted[indptr[d] + p] = src[i];
    } else {
      int n = i - E_EDGES;
      int p = atomicAdd(&cur[n], 1);
      sorted[indptr[n] + p] = n;
    }
  }
}

// ---------- embedding ----------
__global__ __launch_bounds__(128) void k_embed(const float* __restrict__ nf,
                                               const float* __restrict__ W,
                                               const float* __restrict__ b,
                                               const float* __restrict__ g,
                                               const float* __restrict__ bb,
                                               float* __restrict__ x) {
  int n = blockIdx.x, j = threadIdx.x;
  __shared__ float f[F_IN];
  __shared__ float tmp2[2];
  if (j < F_IN) f[j] = nf[n * F_IN + j];
  __syncthreads();
  float acc = b[j];
#pragma unroll
  for (int k = 0; k < F_IN; k++) acc += f[k] * W[k * D + j];
  float s1 = red128_sum(acc, tmp2, j);
  float s2 = red128_sum(acc * acc, tmp2, j);
  float mean = s1 * (1.f / D);
  float var = s2 * (1.f / D) - mean * mean;
  float y = (acc - mean) * rsqrtf(var + 1e-5f) * g[j] + bb[j];
  x[n * D + j] = fmaxf(y, 0.f);
}

// ---------- GAT: h = x@W, a_s, a_d ----------
__global__ __launch_bounds__(128) void k_gat_gemm(const float* __restrict__ x,
                                                  const float* __restrict__ W,
                                                  const float* __restrict__ asrc,
                                                  const float* __restrict__ adst,
                                                  float* __restrict__ h,
                                                  float* __restrict__ a_s,
                                                  float* __restrict__ a_d) {
  int tid = threadIdx.x;
  int r0 = blockIdx.x * 8;
  __shared__ float xs[8][D];
#pragma unroll
  for (int r = 0; r < 8; r++) xs[r][tid] = x[(r0 + r) * D + tid];
  __syncthreads();
  float acc[8];
#pragma unroll
  for (int r = 0; r < 8; r++) acc[r] = 0.f;
  for (int k = 0; k < D; k++) {
    float w = W[k * D + tid];
#pragma unroll
    for (int r = 0; r < 8; r++) acc[r] += xs[r][k] * w;
  }
  float av = asrc[tid], dv = adst[tid];
  int head = tid >> 5;
#pragma unroll
  for (int r = 0; r < 8; r++) {
    h[(r0 + r) * D + tid] = acc[r];
    float p = acc[r] * av;
    float q = acc[r] * dv;
#pragma unroll
    for (int m = 1; m < 32; m <<= 1) { p += __shfl_xor(p, m, 64); q += __shfl_xor(q, m, 64); }
    if ((tid & 31) == 0) {
      a_s[(r0 + r) * H + head] = p;
      a_d[(r0 + r) * H + head] = q;
    }
  }
}

__device__ __forceinline__ float leaky(float v) { return v > 0.f ? v : 0.2f * v; }

// ---------- GAT aggregation + residual + LN (block per dst node) ----------
__global__ __launch_bounds__(128) void k_gat_agg(const float* __restrict__ h,
                                                 const float* __restrict__ a_s,
                                                 const float* __restrict__ a_d,
                                                 const int* __restrict__ indptr,
                                                 const int* __restrict__ sorted,
                                                 const float* __restrict__ gb,
                                                 const float* __restrict__ g,
                                                 const float* __restrict__ bb,
                                                 float* __restrict__ x) {
  int n = blockIdx.x, tid = threadIdx.x;
  int beg = indptr[n], end = indptr[n + 1];
  __shared__ float mxs[H], inv[H];
  __shared__ float rtmp[8];
  __shared__ int s_src[128];
  __shared__ float s_alpha[128 * 4];
  __shared__ float tmp2[2];
  float4 ad = *(const float4*)&a_d[n * H];

  // phase 1: per-head max
  float mx0 = -1e30f, mx1 = -1e30f, mx2 = -1e30f, mx3 = -1e30f;
  for (int e = beg + tid; e < end; e += 128) {
    int s = sorted[e];
    float4 as = *(const float4*)&a_s[s * H];
    mx0 = fmaxf(mx0, leaky(as.x + ad.x));
    mx1 = fmaxf(mx1, leaky(as.y + ad.y));
    mx2 = fmaxf(mx2, leaky(as.z + ad.z));
    mx3 = fmaxf(mx3, leaky(as.w + ad.w));
  }
#pragma unroll
  for (int m = 1; m < 64; m <<= 1) {
    mx0 = fmaxf(mx0, __shfl_xor(mx0, m, 64));
    mx1 = fmaxf(mx1, __shfl_xor(mx1, m, 64));
    mx2 = fmaxf(mx2, __shfl_xor(mx2, m, 64));
    mx3 = fmaxf(mx3, __shfl_xor(mx3, m, 64));
  }
  if ((tid & 63) == 0) {
    int w = tid >> 6;
    rtmp[w * 4 + 0] = mx0; rtmp[w * 4 + 1] = mx1; rtmp[w * 4 + 2] = mx2; rtmp[w * 4 + 3] = mx3;
  }
  __syncthreads();
  if (tid < 4) mxs[tid] = fmaxf(rtmp[tid], rtmp[4 + tid]);
  __syncthreads();

  // phase 2: denom
  float s0 = 0.f, s1 = 0.f, s2 = 0.f, s3 = 0.f;
  for (int e = beg + tid; e < end; e += 128) {
    int s = sorted[e];
    float4 as = *(const float4*)&a_s[s * H];
    s0 += __expf(leaky(as.x + ad.x) - mxs[0]);
    s1 += __expf(leaky(as.y + ad.y) - mxs[1]);
    s2 += __expf(leaky(as.z + ad.z) - mxs[2]);
    s3 += __expf(leaky(as.w + ad.w) - mxs[3]);
  }
#pragma unroll
  for (int m = 1; m < 64; m <<= 1) {
    s0 += __shfl_xor(s0, m, 64);
    s1 += __shfl_xor(s1, m, 64);
    s2 += __shfl_xor(s2, m, 64);
    s3 += __shfl_xor(s3, m, 64);
  }
  __syncthreads();  // rtmp reuse
  if ((tid & 63) == 0) {
    int w = tid >> 6;
    rtmp[w * 4 + 0] = s0; rtmp[w * 4 + 1] = s1; rtmp[w * 4 + 2] = s2; rtmp[w * 4 + 3] = s3;
  }
  __syncthreads();
  if (tid < 4) inv[tid] = 1.f / (rtmp[tid] + rtmp[4 + tid] + 1e-16f);

  // phase 3: weighted aggregation; thread = output channel
  int hd = tid >> 5;
  float acc = 0.f;
  for (int c0 = beg; c0 < end; c0 += 128) {
    __syncthreads();
    int e = c0 + tid;
    if (e < end) {
      int s = sorted[e];
      s_src[tid] = s;
      float4 as = *(const float4*)&a_s[s * H];
      s_alpha[tid * 4 + 0] = __expf(leaky(as.x + ad.x) - mxs[0]) * inv[0];
      s_alpha[tid * 4 + 1] = __expf(leaky(as.y + ad.y) - mxs[1]) * inv[1];
      s_alpha[tid * 4 + 2] = __expf(leaky(as.z + ad.z) - mxs[2]) * inv[2];
      s_alpha[tid * 4 + 3] = __expf(leaky(as.w + ad.w) - mxs[3]) * inv[3];
    }
    __syncthreads();
    int nc = min(128, end - c0);
#pragma unroll 4
    for (int i = 0; i < nc; i++) {
      float al = s_alpha[i * 4 + hd];
      acc += al * h[s_src[i] * D + tid];
    }
  }
  // epilogue: +b, relu, residual, LN
  float out = acc + gb[tid];
  float y = x[n * D + tid] + fmaxf(out, 0.f);
  float t1 = red128_sum(y, tmp2, tid);
  float t2 = red128_sum(y * y, tmp2, tid);
  float mean = t1 * (1.f / D);
  float var = t2 * (1.f / D) - mean * mean;
  x[n * D + tid] = (y - mean) * rsqrtf(var + 1e-5f) * g[tid] + bb[tid];
}

// ---------- q/k/v projections ----------
__global__ __launch_bounds__(128) void k_qkv(const float* __restrict__ x,
                                             const float* __restrict__ pe,
                                             const float* __restrict__ Wq,
                                             const float* __restrict__ Wk,
                                             const float* __restrict__ Wv,
                                             const float* __restrict__ bq,
                                             const float* __restrict__ bk,
                                             const float* __restrict__ bv,
                                             float* __restrict__ q, float* __restrict__ k,
                                             float* __restrict__ v) {
  int tid = threadIdx.x, r0 = blockIdx.x * 8;
  __shared__ float xs[8][D], ps[8][D];
#pragma unroll
  for (int r = 0; r < 8; r++) {
    xs[r][tid] = x[(r0 + r) * D + tid];
    ps[r][tid] = pe[(r0 + r) * D + tid];
  }
  __syncthreads();
  float aq[8], ak[8], av[8];
#pragma unroll
  for (int r = 0; r < 8; r++) { aq[r] = 0.f; ak[r] = 0.f; av[r] = 0.f; }
  for (int kk = 0; kk < D; kk++) {
    float wq = Wq[kk * D + tid], wk = Wk[kk * D + tid], wv = Wv[kk * D + tid];
#pragma unroll
    for (int r = 0; r < 8; r++) {
      aq[r] += xs[r][kk] * wq;
      ak[r] += ps[r][kk] * wk;
      av[r] += ps[r][kk] * wv;
    }
  }
  const float sc = 0.17677669529663689f;  // 1/sqrt(32) folded into q
#pragma unroll
  for (int r = 0; r < 8; r++) {
    q[(r0 + r) * D + tid] = (aq[r] + bq[tid]) * sc;
    k[(r0 + r) * D + tid] = ak[r] + bk[tid];
    v[(r0 + r) * D + tid] = av[r] + bv[tid];
  }
}

// ---------- flash attention (fp32 baseline) ----------
#define QT 64
#define KT 64
__global__ __launch_bounds__(256) void k_attn(const float* __restrict__ qp,
                                              const float* __restrict__ kp,
                                              const float* __restrict__ vp,
                                              float* __restrict__ xa) {
  int hh = blockIdx.y;
  int q0 = blockIdx.x * QT;
  int t = threadIdx.x;
  __shared__ float Qt[C][QT + 4];
  __shared__ float Kt[C][KT + 4];
  __shared__ float Vt[KT][C + 4];
  __shared__ float Pt[QT][KT + 4];
  __shared__ float m_l[QT], l_l[QT], sc_l[QT];
  int cc = t & 31, r8 = t >> 5;
#pragma unroll
  for (int i = 0; i < 8; i++) {
    int qi = r8 + i * 8;
    Qt[cc][qi] = qp[(q0 + qi) * D + hh * C + cc];
  }
  if (t < QT) { m_l[t] = -1e30f; l_l[t] = 0.f; }
  float acc[8];
#pragma unroll
  for (int i = 0; i < 8; i++) acc[i] = 0.f;
  int myq = t >> 2;
  int c0 = (t & 3) * 8;
  int k0 = (t & 3) * 16;

  for (int kt0 = 0; kt0 < N_NODES; kt0 += KT) {
    __syncthreads();  // previous PV done before restage
#pragma unroll
    for (int i = 0; i < 8; i++) {
      int ki = r8 + i * 8;
      Kt[cc][ki] = kp[(kt0 + ki) * D + hh * C + cc];
      Vt[ki][cc] = vp[(kt0 + ki) * D + hh * C + cc];
    }
    __syncthreads();
    // S = q . k (each thread: 1 query x 16 keys)
    float s[16];
#pragma unroll
    for (int i = 0; i < 16; i++) s[i] = 0.f;
    for (int c2 = 0; c2 < C; c2++) {
      float qv = Qt[c2][myq];
      float4 k4a = *(float4*)&Kt[c2][k0];
      float4 k4b = *(float4*)&Kt[c2][k0 + 4];
      float4 k4c = *(float4*)&Kt[c2][k0 + 8];
      float4 k4d = *(float4*)&Kt[c2][k0 + 12];
      s[0] += qv * k4a.x;  s[1] += qv * k4a.y;  s[2] += qv * k4a.z;  s[3] += qv * k4a.w;
      s[4] += qv * k4b.x;  s[5] += qv * k4b.y;  s[6] += qv * k4b.z;  s[7] += qv * k4b.w;
      s[8] += qv * k4c.x;  s[9] += qv * k4c.y;  s[10] += qv * k4c.z; s[11] += qv * k4c.w;
      s[12] += qv * k4d.x; s[13] += qv * k4d.y; s[14] += qv * k4d.z; s[15] += qv * k4d.w;
    }
    float mloc = s[0];
#pragma unroll
    for (int i = 1; i < 16; i++) mloc = fmaxf(mloc, s[i]);
    mloc = fmaxf(mloc, __shfl_xor(mloc, 1, 64));
    mloc = fmaxf(mloc, __shfl_xor(mloc, 2, 64));
    float m_old = m_l[myq];
    float m_new = fmaxf(m_old, mloc);
    float psum = 0.f;
#pragma unroll
    for (int i = 0; i < 16; i++) { s[i] = __expf(s[i] - m_new); psum += s[i]; }
    *(float4*)&Pt[myq][k0]      = make_float4(s[0], s[1], s[2], s[3]);
    *(float4*)&Pt[myq][k0 + 4]  = make_float4(s[4], s[5], s[6], s[7]);
    *(float4*)&Pt[myq][k0 + 8]  = make_float4(s[8], s[9], s[10], s[11]);
    *(float4*)&Pt[myq][k0 + 12] = make_float4(s[12], s[13], s[14], s[15]);
    psum += __shfl_xor(psum, 1, 64);
    psum += __shfl_xor(psum, 2, 64);
    if ((t & 3) == 0) {
      float scf = __expf(m_old - m_new);
      sc_l[myq] = scf;
      l_l[myq] = l_l[myq] * scf + psum;
      m_l[myq] = m_new;
    }
    __syncthreads();
    float scf = sc_l[myq];
#pragma unroll
    for (int i = 0; i < 8; i++) acc[i] *= scf;
    for (int kk = 0; kk < KT; kk++) {
      float pv = Pt[myq][kk];
      float4 v4a = *(float4*)&Vt[kk][c0];
      float4 v4b = *(float4*)&Vt[kk][c0 + 4];
      acc[0] += pv * v4a.x; acc[1] += pv * v4a.y; acc[2] += pv * v4a.z; acc[3] += pv * v4a.w;
      acc[4] += pv * v4b.x; acc[5] += pv * v4b.y; acc[6] += pv * v4b.z; acc[7] += pv * v4b.w;
    }
  }
  float invl = 1.f / l_l[myq];
  int col = hh * C + c0;
  float4 o1 = make_float4(acc[0] * invl, acc[1] * invl, acc[2] * invl, acc[3] * invl);
  float4 o2 = make_float4(acc[4] * invl, acc[5] * invl, acc[6] * invl, acc[7] * invl);
  *(float4*)&xa[(q0 + myq) * D + col] = o1;
  *(float4*)&xa[(q0 + myq) * D + col + 4] = o2;
}

// ---------- Wo + residual + LN + pooled partial ----------
__global__ __launch_bounds__(128) void k_ca(const float* __restrict__ xa,
                                            const float* __restrict__ Wo,
                                            const float* __restrict__ bo,
                                            const float* __restrict__ g,
                                            const float* __restrict__ bb,
                                            float* __restrict__ x, float* __restrict__ pooled,
                                            float* __restrict__ outx) {
  int tid = threadIdx.x, r0 = blockIdx.x * 8;
  __shared__ float xs[8][D];
  __shared__ float tmp2[2];
#pragma unroll
  for (int r = 0; r < 8; r++) xs[r][tid] = xa[(r0 + r) * D + tid];
  __syncthreads();
  float acc[8];
#pragma unroll
  for (int r = 0; r < 8; r++) acc[r] = bo[tid];
  for (int kk = 0; kk < D; kk++) {
    float w = Wo[kk * D + tid];
#pragma unroll
    for (int r = 0; r < 8; r++) acc[r] += xs[r][kk] * w;
  }
  float gv = g[tid], bv = bb[tid];
  float psum = 0.f;
#pragma unroll
  for (int r = 0; r < 8; r++) {
    float y = x[(r0 + r) * D + tid] + acc[r];
    float t1 = red128_sum(y, tmp2, tid);
    float t2 = red128_sum(y * y, tmp2, tid);
    float mean = t1 * (1.f / D);
    float var = t2 * (1.f / D) - mean * mean;
    float o = (y - mean) * rsqrtf(var + 1e-5f) * gv + bv;
    x[(r0 + r) * D + tid] = o;
    outx[(r0 + r) * D + tid] = o;
    psum += o;
  }
  atomicAdd(&pooled[tid], psum);
}

// ---------- policy head (block per query node) ----------
__global__ __launch_bounds__(128) void k_policy(const float* __restrict__ x,
                                                const float* __restrict__ W1,
                                                const float* __restrict__ b1,
                                                const float* __restrict__ W2,
                                                const float* __restrict__ b2,
                                                const float* __restrict__ W3,
                                                const float* __restrict__ b3,
                                                float* __restrict__ logits) {
  int n = blockIdx.x, tid = threadIdx.x;
  __shared__ float xs[D], h1[D], h2[64];
  xs[tid] = x[n * D + tid];
  __syncthreads();
  float a = b1[tid];
  for (int kk = 0; kk < D; kk++) a += xs[kk] * W1[kk * D + tid];
  h1[tid] = fmaxf(a, 0.f);
  __syncthreads();
  if (tid < 64) {
    float a2 = b2[tid];
    for (int kk = 0; kk < D; kk++) a2 += h1[kk] * W2[kk * 64 + tid];
    h2[tid] = fmaxf(a2, 0.f);
  }
  __syncthreads();
  float p0 = 0.f, p1 = 0.f;
  if (tid < 64) { p0 = h2[tid] * W3[tid * 2]; p1 = h2[tid] * W3[tid * 2 + 1]; }
#pragma unroll
  for (int m = 1; m < 64; m <<= 1) { p0 += __shfl_xor(p0, m, 64); p1 += __shfl_xor(p1, m, 64); }
  if (tid == 0) {
    logits[n * 2] = p0 + b3[0];
    logits[n * 2 + 1] = p1 + b3[1];
  }
}

// ---------- value head (single block) ----------
__global__ __launch_bounds__(128) void k_value(const float* __restrict__ pooled,
                                               const float* __restrict__ W1,
                                               const float* __restrict__ b1,
                                               const float* __restrict__ W2,
                                               const float* __restrict__ b2,
                                               const float* __restrict__ W3,
                                               const float* __restrict__ b3,
                                               float* __restrict__ val) {
  int tid = threadIdx.x;
  __shared__ float ps[D], v1[D], v2[64];
  ps[tid] = pooled[tid] * (1.f / N_NODES);
  __syncthreads();
  float a = b1[tid];
  for (int kk = 0; kk < D; kk++) a += ps[kk] * W1[kk * D + tid];
  v1[tid] = fmaxf(a, 0.f);
  __syncthreads();
  if (tid < 64) {
    float a2 = b2[tid];
    for (int kk = 0; kk < D; kk++) a2 += v1[kk] * W2[kk * 64 + tid];
    v2[tid] = fmaxf(a2, 0.f);
  }
  __syncthreads();
  float p = (tid < 64) ? v2[tid] * W3[tid] : 0.f;
#pragma unroll
  for (int m = 1; m < 64; m <<= 1) p += __shfl_xor(p, m, 64);
  if (tid == 0) val[0] = p + b3[0];
}

extern "C" void kernel_launch(void* const* d_in, const int* in_sizes, int n_in,
                              void* d_out, int out_size, void* d_ws, size_t ws_size,
                              hipStream_t stream) {
  const float* nf   = (const float*)d_in[0];
  const int*   ei   = (const int*)d_in[1];
  const float* pe   = (const float*)d_in[2];
  const float* embW = (const float*)d_in[3];
  const float* embB = (const float*)d_in[4];
  const float* elng = (const float*)d_in[5];
  const float* elnb = (const float*)d_in[6];
  const float* gatW = (const float*)d_in[7];
  const float* aS   = (const float*)d_in[8];
  const float* aD   = (const float*)d_in[9];
  const float* gatB = (const float*)d_in[10];
  const float* lng  = (const float*)d_in[11];
  const float* lnb  = (const float*)d_in[12];
  const float* Wq   = (const float*)d_in[13];
  const float* Wk   = (const float*)d_in[14];
  const float* Wv   = (const float*)d_in[15];
  const float* Wo   = (const float*)d_in[16];
  const float* bq   = (const float*)d_in[17];
  const float* bk   = (const float*)d_in[18];
  const float* bv   = (const float*)d_in[19];
  const float* bo   = (const float*)d_in[20];
  const float* cag  = (const float*)d_in[21];
  const float* cab  = (const float*)d_in[22];
  const float* pW1  = (const float*)d_in[23];
  const float* pb1  = (const float*)d_in[24];
  const float* pW2  = (const float*)d_in[25];
  const float* pb2  = (const float*)d_in[26];
  const float* pW3  = (const float*)d_in[27];
  const float* pb3  = (const float*)d_in[28];
  const float* vW1  = (const float*)d_in[29];
  const float* vb1  = (const float*)d_in[30];
  const float* vW2  = (const float*)d_in[31];
  const float* vb2  = (const float*)d_in[32];
  const float* vW3  = (const float*)d_in[33];
  const float* vb3  = (const float*)d_in[34];

  // workspace layout (~17.7 MB): all fp32 buffers then int CSR arrays
  float* fw = (float*)d_ws;
  float* x    = fw; fw += N_NODES * D;
  float* hbuf = fw; fw += N_NODES * D;   // reused as xa after GAT layers
  float* a_s  = fw; fw += N_NODES * H;
  float* a_d  = fw; fw += N_NODES * H;
  float* qb   = fw; fw += N_NODES * D;
  float* kb   = fw; fw += N_NODES * D;
  float* vbuf = fw; fw += N_NODES * D;
  float* pooled = fw; fw += 128;
  int* ib     = (int*)fw;
  int* cnt    = ib; ib += N_NODES;
  int* cur    = ib; ib += N_NODES;
  int* indptr = ib; ib += N_NODES + 16;
  int* sorted = ib;

  float* out    = (float*)d_out;
  float* logits = out;
  float* val    = out + NQ_ * 2;
  float* outx   = out + NQ_ * 2 + 1;

  const int* esrc = ei;
  const int* edst = ei + E_EDGES;

  hipLaunchKernelGGL(k_zero, dim3(24), dim3(256), 0, stream, cnt, cur, pooled);
  hipLaunchKernelGGL(k_hist, dim3(512), dim3(256), 0, stream, edst, cnt);
  hipLaunchKernelGGL(k_scan, dim3(1), dim3(256), 0, stream, cnt, indptr);
  hipLaunchKernelGGL(k_scatter, dim3(512), dim3(256), 0, stream, esrc, edst, indptr, cur, sorted);
  hipLaunchKernelGGL(k_embed, dim3(N_NODES), dim3(128), 0, stream, nf, embW, embB, elng, elnb, x);
  for (int l = 0; l < L_LAYERS; l++) {
    hipLaunchKernelGGL(k_gat_gemm, dim3(N_NODES / 8), dim3(128), 0, stream,
                       x, gatW + l * D * D, aS + l * D, aD + l * D, hbuf, a_s, a_d);
    hipLaunchKernelGGL(k_gat_agg, dim3(N_NODES), dim3(128), 0, stream,
                       hbuf, a_s, a_d, indptr, sorted, gatB + l * D, lng + l * D, lnb + l * D, x);
  }
  hipLaunchKernelGGL(k_qkv, dim3(N_NODES / 8), dim3(128), 0, stream,
                     x, pe, Wq, Wk, Wv, bq, bk, bv, qb, kb, vbuf);
  // attention writes into hbuf (free after GAT layers)
  hipLaunchKernelGGL(k_attn, dim3(N_NODES / QT, H), dim3(256), 0, stream, qb, kb, vbuf, hbuf);
  hipLaunchKernelGGL(k_ca, dim3(N_NODES / 8), dim3(128), 0, stream,
                     hbuf, Wo, bo, cag, cab, x, pooled, outx);
  hipLaunchKernelGGL(k_policy, dim3(NQ_), dim3(128), 0, stream,
                     x, pW1, pb1, pW2, pb2, pW3, pb3, logits);
  hipLaunchKernelGGL(k_value, dim3(1), dim3(128), 0, stream,
                     pooled, vW1, vb1, vW2, vb2, vW3, vb3, val);
}

// Round 2
// 446.801 us; speedup vs baseline: 1.8705x; 1.8705x over previous
//
#include <hip/hip_runtime.h>
#include <hip/hip_bf16.h>

#define N_NODES 6144
#define NQ_ 3072
#define D 128
#define H 4
#define C 32
#define F_IN 10
#define L_LAYERS 4
#define E_EDGES 393216
#define E_TOT (E_EDGES + N_NODES)

typedef __attribute__((ext_vector_type(8))) short bf16x8;
typedef __attribute__((ext_vector_type(4))) float f32x4;

__device__ __forceinline__ unsigned short f2bf(float f) {
  unsigned u = __float_as_uint(f);
  unsigned r = (u + 0x7fffu + ((u >> 16) & 1u)) >> 16;
  return (unsigned short)r;
}

// ---------- helpers ----------
__device__ __forceinline__ float red128_sum(float v, float* tmp2, int tid) {
#pragma unroll
  for (int m = 1; m < 64; m <<= 1) v += __shfl_xor(v, m, 64);
  __syncthreads();                 // protect tmp2 reuse across calls
  if ((tid & 63) == 0) tmp2[tid >> 6] = v;
  __syncthreads();
  return tmp2[0] + tmp2[1];
}

// ---------- CSR build ----------
__global__ void k_zero(int* cnt, int* cur, float* pooled) {
  int i = blockIdx.x * blockDim.x + threadIdx.x;
  if (i < N_NODES) { cnt[i] = 0; cur[i] = 0; }
  if (i < D) pooled[i] = 0.f;
}

__global__ void k_hist(const int* __restrict__ dst, int* __restrict__ cnt) {
  for (int i = blockIdx.x * blockDim.x + threadIdx.x; i < E_EDGES; i += gridDim.x * blockDim.x)
    atomicAdd(&cnt[dst[i]], 1);
}

__global__ void k_scan(const int* __restrict__ cnt, int* __restrict__ indptr) {
  __shared__ int ps[256];
  int tid = threadIdx.x;
  const int CH = N_NODES / 256;  // 24
  int base = tid * CH;
  int loc[CH];
  int s = 0;
#pragma unroll
  for (int i = 0; i < CH; i++) { loc[i] = cnt[base + i] + 1; s += loc[i]; }  // +1 self loop
  ps[tid] = s;
  __syncthreads();
  for (int off = 1; off < 256; off <<= 1) {
    int v = (tid >= off) ? ps[tid - off] : 0;
    __syncthreads();
    ps[tid] += v;
    __syncthreads();
  }
  int run = (tid == 0) ? 0 : ps[tid - 1];
#pragma unroll
  for (int i = 0; i < CH; i++) { indptr[base + i] = run; run += loc[i]; }
  if (tid == 255) indptr[N_NODES] = run;
}

__global__ void k_scatter(const int* __restrict__ src, const int* __restrict__ dst,
                          const int* __restrict__ indptr, int* __restrict__ cur,
                          int* __restrict__ sorted) {
  for (int i = blockIdx.x * blockDim.x + threadIdx.x; i < E_TOT; i += gridDim.x * blockDim.x) {
    if (i < E_EDGES) {
      int d = dst[i];
      int p = atomicAdd(&cur[d], 1);
      sorted[indptr[d] + p] = src[i];
    } else {
      int n = i - E_EDGES;
      int p = atomicAdd(&cur[n], 1);
      sorted[indptr[n] + p] = n;
    }
  }
}

// ---------- embedding ----------
__global__ __launch_bounds__(128) void k_embed(const float* __restrict__ nf,
                                               const float* __restrict__ W,
                                               const float* __restrict__ b,
                                               const float* __restrict__ g,
                                               const float* __restrict__ bb,
                                               float* __restrict__ x) {
  int n = blockIdx.x, j = threadIdx.x;
  __shared__ float f[F_IN];
  __shared__ float tmp2[2];
  if (j < F_IN) f[j] = nf[n * F_IN + j];
  __syncthreads();
  float acc = b[j];
#pragma unroll
  for (int k = 0; k < F_IN; k++) acc += f[k] * W[k * D + j];
  float s1 = red128_sum(acc, tmp2, j);
  float s2 = red128_sum(acc * acc, tmp2, j);
  float mean = s1 * (1.f / D);
  float var = s2 * (1.f / D) - mean * mean;
  float y = (acc - mean) * rsqrtf(var + 1e-5f) * g[j] + bb[j];
  x[n * D + j] = fmaxf(y, 0.f);
}

// ---------- GAT: h = x@W, a_s, a_d ----------
__global__ __launch_bounds__(128) void k_gat_gemm(const float* __restrict__ x,
                                                  const float* __restrict__ W,
                                                  const float* __restrict__ asrc,
                                                  const float* __restrict__ adst,
                                                  float* __restrict__ h,
                                                  float* __restrict__ a_s,
                                                  float* __restrict__ a_d) {
  int tid = threadIdx.x;
  int r0 = blockIdx.x * 8;
  __shared__ float xs[8][D];
#pragma unroll
  for (int r = 0; r < 8; r++) xs[r][tid] = x[(r0 + r) * D + tid];
  __syncthreads();
  float acc[8];
#pragma unroll
  for (int r = 0; r < 8; r++) acc[r] = 0.f;
  for (int k = 0; k < D; k++) {
    float w = W[k * D + tid];
#pragma unroll
    for (int r = 0; r < 8; r++) acc[r] += xs[r][k] * w;
  }
  float av = asrc[tid], dv = adst[tid];
  int head = tid >> 5;
#pragma unroll
  for (int r = 0; r < 8; r++) {
    h[(r0 + r) * D + tid] = acc[r];
    float p = acc[r] * av;
    float q = acc[r] * dv;
#pragma unroll
    for (int m = 1; m < 32; m <<= 1) { p += __shfl_xor(p, m, 64); q += __shfl_xor(q, m, 64); }
    if ((tid & 31) == 0) {
      a_s[(r0 + r) * H + head] = p;
      a_d[(r0 + r) * H + head] = q;
    }
  }
}

__device__ __forceinline__ float leaky(float v) { return v > 0.f ? v : 0.2f * v; }

// ---------- GAT aggregation + residual + LN (block per dst node) ----------
__global__ __launch_bounds__(128) void k_gat_agg(const float* __restrict__ h,
                                                 const float* __restrict__ a_s,
                                                 const float* __restrict__ a_d,
                                                 const int* __restrict__ indptr,
                                                 const int* __restrict__ sorted,
                                                 const float* __restrict__ gb,
                                                 const float* __restrict__ g,
                                                 const float* __restrict__ bb,
                                                 float* __restrict__ x) {
  int n = blockIdx.x, tid = threadIdx.x;
  int beg = indptr[n], end = indptr[n + 1];
  __shared__ float mxs[H], inv[H];
  __shared__ float rtmp[8];
  __shared__ int s_src[128];
  __shared__ float s_alpha[128 * 4];
  __shared__ float tmp2[2];
  float4 ad = *(const float4*)&a_d[n * H];

  // phase 1: per-head max
  float mx0 = -1e30f, mx1 = -1e30f, mx2 = -1e30f, mx3 = -1e30f;
  for (int e = beg + tid; e < end; e += 128) {
    int s = sorted[e];
    float4 as = *(const float4*)&a_s[s * H];
    mx0 = fmaxf(mx0, leaky(as.x + ad.x));
    mx1 = fmaxf(mx1, leaky(as.y + ad.y));
    mx2 = fmaxf(mx2, leaky(as.z + ad.z));
    mx3 = fmaxf(mx3, leaky(as.w + ad.w));
  }
#pragma unroll
  for (int m = 1; m < 64; m <<= 1) {
    mx0 = fmaxf(mx0, __shfl_xor(mx0, m, 64));
    mx1 = fmaxf(mx1, __shfl_xor(mx1, m, 64));
    mx2 = fmaxf(mx2, __shfl_xor(mx2, m, 64));
    mx3 = fmaxf(mx3, __shfl_xor(mx3, m, 64));
  }
  if ((tid & 63) == 0) {
    int w = tid >> 6;
    rtmp[w * 4 + 0] = mx0; rtmp[w * 4 + 1] = mx1; rtmp[w * 4 + 2] = mx2; rtmp[w * 4 + 3] = mx3;
  }
  __syncthreads();
  if (tid < 4) mxs[tid] = fmaxf(rtmp[tid], rtmp[4 + tid]);
  __syncthreads();

  // phase 2: denom
  float s0 = 0.f, s1 = 0.f, s2 = 0.f, s3 = 0.f;
  for (int e = beg + tid; e < end; e += 128) {
    int s = sorted[e];
    float4 as = *(const float4*)&a_s[s * H];
    s0 += __expf(leaky(as.x + ad.x) - mxs[0]);
    s1 += __expf(leaky(as.y + ad.y) - mxs[1]);
    s2 += __expf(leaky(as.z + ad.z) - mxs[2]);
    s3 += __expf(leaky(as.w + ad.w) - mxs[3]);
  }
#pragma unroll
  for (int m = 1; m < 64; m <<= 1) {
    s0 += __shfl_xor(s0, m, 64);
    s1 += __shfl_xor(s1, m, 64);
    s2 += __shfl_xor(s2, m, 64);
    s3 += __shfl_xor(s3, m, 64);
  }
  __syncthreads();  // rtmp reuse
  if ((tid & 63) == 0) {
    int w = tid >> 6;
    rtmp[w * 4 + 0] = s0; rtmp[w * 4 + 1] = s1; rtmp[w * 4 + 2] = s2; rtmp[w * 4 + 3] = s3;
  }
  __syncthreads();
  if (tid < 4) inv[tid] = 1.f / (rtmp[tid] + rtmp[4 + tid] + 1e-16f);

  // phase 3: weighted aggregation; thread = output channel
  int hd = tid >> 5;
  float acc = 0.f;
  for (int c0 = beg; c0 < end; c0 += 128) {
    __syncthreads();
    int e = c0 + tid;
    if (e < end) {
      int s = sorted[e];
      s_src[tid] = s;
      float4 as = *(const float4*)&a_s[s * H];
      s_alpha[tid * 4 + 0] = __expf(leaky(as.x + ad.x) - mxs[0]) * inv[0];
      s_alpha[tid * 4 + 1] = __expf(leaky(as.y + ad.y) - mxs[1]) * inv[1];
      s_alpha[tid * 4 + 2] = __expf(leaky(as.z + ad.z) - mxs[2]) * inv[2];
      s_alpha[tid * 4 + 3] = __expf(leaky(as.w + ad.w) - mxs[3]) * inv[3];
    }
    __syncthreads();
    int nc = min(128, end - c0);
#pragma unroll 4
    for (int i = 0; i < nc; i++) {
      float al = s_alpha[i * 4 + hd];
      acc += al * h[s_src[i] * D + tid];
    }
  }
  // epilogue: +b, relu, residual, LN
  float out = acc + gb[tid];
  float y = x[n * D + tid] + fmaxf(out, 0.f);
  float t1 = red128_sum(y, tmp2, tid);
  float t2 = red128_sum(y * y, tmp2, tid);
  float mean = t1 * (1.f / D);
  float var = t2 * (1.f / D) - mean * mean;
  x[n * D + tid] = (y - mean) * rsqrtf(var + 1e-5f) * g[tid] + bb[tid];
}

// ---------- q/k/v projections -> bf16 q (scaled), bf16 K, bf16 V^T ----------
__global__ __launch_bounds__(128) void k_qkv(const float* __restrict__ x,
                                             const float* __restrict__ pe,
                                             const float* __restrict__ Wq,
                                             const float* __restrict__ Wk,
                                             const float* __restrict__ Wv,
                                             const float* __restrict__ bq,
                                             const float* __restrict__ bk,
                                             const float* __restrict__ bv,
                                             unsigned short* __restrict__ qbf,
                                             unsigned short* __restrict__ kbf,
                                             unsigned short* __restrict__ vtb) {
  int tid = threadIdx.x, r0 = blockIdx.x * 8;
  __shared__ float xs[8][D], ps[8][D];
#pragma unroll
  for (int r = 0; r < 8; r++) {
    xs[r][tid] = x[(r0 + r) * D + tid];
    ps[r][tid] = pe[(r0 + r) * D + tid];
  }
  __syncthreads();
  float aq[8], ak[8], av[8];
#pragma unroll
  for (int r = 0; r < 8; r++) { aq[r] = 0.f; ak[r] = 0.f; av[r] = 0.f; }
  for (int kk = 0; kk < D; kk++) {
    float wq = Wq[kk * D + tid], wk = Wk[kk * D + tid], wv = Wv[kk * D + tid];
#pragma unroll
    for (int r = 0; r < 8; r++) {
      aq[r] += xs[r][kk] * wq;
      ak[r] += ps[r][kk] * wk;
      av[r] += ps[r][kk] * wv;
    }
  }
  const float sc = 0.17677669529663689f;  // 1/sqrt(32) folded into q
  float bqv = bq[tid], bkv = bk[tid], bvv = bv[tid];
#pragma unroll
  for (int r = 0; r < 8; r++) {
    qbf[(r0 + r) * D + tid] = f2bf((aq[r] + bqv) * sc);
    kbf[(r0 + r) * D + tid] = f2bf(ak[r] + bkv);
  }
  // V^T: thread tid owns channel tid for rows r0..r0+7 -> one 16B store
  unsigned u0 = (unsigned)f2bf(av[0] + bvv) | ((unsigned)f2bf(av[1] + bvv) << 16);
  unsigned u1 = (unsigned)f2bf(av[2] + bvv) | ((unsigned)f2bf(av[3] + bvv) << 16);
  unsigned u2 = (unsigned)f2bf(av[4] + bvv) | ((unsigned)f2bf(av[5] + bvv) << 16);
  unsigned u3 = (unsigned)f2bf(av[6] + bvv) | ((unsigned)f2bf(av[7] + bvv) << 16);
  uint4 uu = make_uint4(u0, u1, u2, u3);
  *(uint4*)(vtb + (size_t)tid * N_NODES + r0) = uu;
}

// ---------- flash attention, bf16 MFMA ----------
#define MFMA16(A, B, CIN) __builtin_amdgcn_mfma_f32_16x16x32_bf16(A, B, CIN, 0, 0, 0)
#define REDMAX4(v) { v = fmaxf(v, __shfl_xor(v, 1)); v = fmaxf(v, __shfl_xor(v, 2)); \
                     v = fmaxf(v, __shfl_xor(v, 4)); v = fmaxf(v, __shfl_xor(v, 8)); }
#define REDSUM4(v) { v += __shfl_xor(v, 1); v += __shfl_xor(v, 2); \
                     v += __shfl_xor(v, 4); v += __shfl_xor(v, 8); }

// store one softmax row-register (4 key-blocks) to swizzled P_lds
#define PSTORE(RR, a0, a1, a2, a3) do { \
  int row_ = lg * 4 + (RR); \
  int xr_ = (row_ & 7) << 4; \
  char* rp_ = pb + row_ * 128 + ((lr * 2) ^ (xr_ & 0x10)); \
  int bx_ = xr_ & 0x60; \
  *(unsigned short*)(rp_ + (0 ^ bx_))  = f2bf(a0); \
  *(unsigned short*)(rp_ + (32 ^ bx_)) = f2bf(a1); \
  *(unsigned short*)(rp_ + (64 ^ bx_)) = f2bf(a2); \
  *(unsigned short*)(rp_ + (96 ^ bx_)) = f2bf(a3); \
} while (0)

#define ATTN_TILE(K0, K1, K2, K3, V0, V1, V2, V3) do { \
  f32x4 zz = {0.f, 0.f, 0.f, 0.f}; \
  f32x4 s0 = MFMA16(aq, K0, zz); \
  f32x4 s1 = MFMA16(aq, K1, zz); \
  f32x4 s2 = MFMA16(aq, K2, zz); \
  f32x4 s3 = MFMA16(aq, K3, zz); \
  float x0 = fmaxf(fmaxf(s0[0], s1[0]), fmaxf(s2[0], s3[0])); \
  float x1 = fmaxf(fmaxf(s0[1], s1[1]), fmaxf(s2[1], s3[1])); \
  float x2 = fmaxf(fmaxf(s0[2], s1[2]), fmaxf(s2[2], s3[2])); \
  float x3 = fmaxf(fmaxf(s0[3], s1[3]), fmaxf(s2[3], s3[3])); \
  REDMAX4(x0); REDMAX4(x1); REDMAX4(x2); REDMAX4(x3); \
  float n0 = fmaxf(m0, x0), n1 = fmaxf(m1, x1), n2 = fmaxf(m2, x2), n3 = fmaxf(m3, x3); \
  float c0_ = __expf(m0 - n0), c1_ = __expf(m1 - n1), c2_ = __expf(m2 - n2), c3_ = __expf(m3 - n3); \
  m0 = n0; m1 = n1; m2 = n2; m3 = n3; \
  float q00 = __expf(s0[0] - n0), q01 = __expf(s1[0] - n0), q02 = __expf(s2[0] - n0), q03 = __expf(s3[0] - n0); \
  float q10 = __expf(s0[1] - n1), q11 = __expf(s1[1] - n1), q12 = __expf(s2[1] - n1), q13 = __expf(s3[1] - n1); \
  float q20 = __expf(s0[2] - n2), q21 = __expf(s1[2] - n2), q22 = __expf(s2[2] - n2), q23 = __expf(s3[2] - n2); \
  float q30 = __expf(s0[3] - n3), q31 = __expf(s1[3] - n3), q32 = __expf(s2[3] - n3), q33 = __expf(s3[3] - n3); \
  float t0_ = q00 + q01 + q02 + q03, t1_ = q10 + q11 + q12 + q13; \
  float t2_ = q20 + q21 + q22 + q23, t3_ = q30 + q31 + q32 + q33; \
  REDSUM4(t0_); REDSUM4(t1_); REDSUM4(t2_); REDSUM4(t3_); \
  l0 = l0 * c0_ + t0_; l1 = l1 * c1_ + t1_; l2 = l2 * c2_ + t2_; l3 = l3 * c3_ + t3_; \
  PSTORE(0, q00, q01, q02, q03); \
  PSTORE(1, q10, q11, q12, q13); \
  PSTORE(2, q20, q21, q22, q23); \
  PSTORE(3, q30, q31, q32, q33); \
  o0[0] *= c0_; o0[1] *= c1_; o0[2] *= c2_; o0[3] *= c3_; \
  o1[0] *= c0_; o1[1] *= c1_; o1[2] *= c2_; o1[3] *= c3_; \
  bf16x8 pa0 = *(const bf16x8*)(pb + pr0); \
  bf16x8 pa1 = *(const bf16x8*)(pb + pr1); \
  o0 = MFMA16(pa0, V0, o0); \
  o1 = MFMA16(pa0, V1, o1); \
  o0 = MFMA16(pa1, V2, o0); \
  o1 = MFMA16(pa1, V3, o1); \
} while (0)

#define LOADKV(K0, K1, K2, K3, V0, V1, V2, V3, KT0) do { \
  const unsigned short* kp_ = kB + (size_t)(KT0) * D; \
  K0 = *(const bf16x8*)(kp_); \
  K1 = *(const bf16x8*)(kp_ + 16 * D); \
  K2 = *(const bf16x8*)(kp_ + 32 * D); \
  K3 = *(const bf16x8*)(kp_ + 48 * D); \
  V0 = *(const bf16x8*)(vB0 + (KT0)); \
  V1 = *(const bf16x8*)(vB1 + (KT0)); \
  V2 = *(const bf16x8*)(vB0 + (KT0) + 32); \
  V3 = *(const bf16x8*)(vB1 + (KT0) + 32); \
} while (0)

__global__ __launch_bounds__(128) void k_attn_mfma(const unsigned short* __restrict__ qbf,
                                                   const unsigned short* __restrict__ kbf,
                                                   const unsigned short* __restrict__ vtb,
                                                   float* __restrict__ xa) {
  int hh = blockIdx.y;
  int q0 = blockIdx.x * 32;
  int t = threadIdx.x;
  int wv = t >> 6, l = t & 63, lr = l & 15, lg = l >> 4;
  __shared__ unsigned short P_lds[2][16][64];
  char* pb = (char*)(&P_lds[wv][0][0]);

  bf16x8 aq = *(const bf16x8*)(qbf + (size_t)(q0 + wv * 16 + lr) * D + hh * 32 + lg * 8);
  const unsigned short* kB = kbf + (size_t)lr * D + hh * 32 + lg * 8;
  const unsigned short* vB0 = vtb + (size_t)(hh * 32 + lr) * N_NODES + lg * 8;
  const unsigned short* vB1 = vB0 + 16 * N_NODES;
  int xr2 = (lr & 7) << 4;
  int pr0 = lr * 128 + ((lg * 16) ^ xr2);
  int pr1 = lr * 128 + ((64 + lg * 16) ^ xr2);

  f32x4 o0 = {0.f, 0.f, 0.f, 0.f}, o1 = {0.f, 0.f, 0.f, 0.f};
  float m0 = -3e38f, m1 = -3e38f, m2 = -3e38f, m3 = -3e38f;
  float l0 = 0.f, l1 = 0.f, l2 = 0.f, l3 = 0.f;

  bf16x8 ka0, ka1, ka2, ka3, va0, va1, va2, va3;
  bf16x8 kb0, kb1, kb2, kb3, vb0, vb1, vb2, vb3;
  LOADKV(ka0, ka1, ka2, ka3, va0, va1, va2, va3, 0);
  for (int it = 0; it < 96; it += 2) {
    LOADKV(kb0, kb1, kb2, kb3, vb0, vb1, vb2, vb3, (it + 1) * 64);
    ATTN_TILE(ka0, ka1, ka2, ka3, va0, va1, va2, va3);
    if (it + 2 < 96) LOADKV(ka0, ka1, ka2, ka3, va0, va1, va2, va3, (it + 2) * 64);
    ATTN_TILE(kb0, kb1, kb2, kb3, vb0, vb1, vb2, vb3);
  }

  float i0 = 1.f / l0, i1 = 1.f / l1, i2 = 1.f / l2, i3 = 1.f / l3;
  float* op = xa + (size_t)(q0 + wv * 16 + lg * 4) * D + hh * 32 + lr;
  op[0]         = o0[0] * i0;
  op[D]         = o0[1] * i1;
  op[2 * D]     = o0[2] * i2;
  op[3 * D]     = o0[3] * i3;
  op[16]        = o1[0] * i0;
  op[D + 16]    = o1[1] * i1;
  op[2 * D + 16] = o1[2] * i2;
  op[3 * D + 16] = o1[3] * i3;
}

// ---------- Wo + residual + LN + pooled partial ----------
__global__ __launch_bounds__(128) void k_ca(const float* __restrict__ xa,
                                            const float* __restrict__ Wo,
                                            const float* __restrict__ bo,
                                            const float* __restrict__ g,
                                            const float* __restrict__ bb,
                                            float* __restrict__ x, float* __restrict__ pooled,
                                            float* __restrict__ outx) {
  int tid = threadIdx.x, r0 = blockIdx.x * 8;
  __shared__ float xs[8][D];
  __shared__ float tmp2[2];
#pragma unroll
  for (int r = 0; r < 8; r++) xs[r][tid] = xa[(r0 + r) * D + tid];
  __syncthreads();
  float acc[8];
#pragma unroll
  for (int r = 0; r < 8; r++) acc[r] = bo[tid];
  for (int kk = 0; kk < D; kk++) {
    float w = Wo[kk * D + tid];
#pragma unroll
    for (int r = 0; r < 8; r++) acc[r] += xs[r][kk] * w;
  }
  float gv = g[tid], bv = bb[tid];
  float psum = 0.f;
#pragma unroll
  for (int r = 0; r < 8; r++) {
    float y = x[(r0 + r) * D + tid] + acc[r];
    float t1 = red128_sum(y, tmp2, tid);
    float t2 = red128_sum(y * y, tmp2, tid);
    float mean = t1 * (1.f / D);
    float var = t2 * (1.f / D) - mean * mean;
    float o = (y - mean) * rsqrtf(var + 1e-5f) * gv + bv;
    x[(r0 + r) * D + tid] = o;
    outx[(r0 + r) * D + tid] = o;
    psum += o;
  }
  atomicAdd(&pooled[tid], psum);
}

// ---------- policy head (block per query node) ----------
__global__ __launch_bounds__(128) void k_policy(const float* __restrict__ x,
                                                const float* __restrict__ W1,
                                                const float* __restrict__ b1,
                                                const float* __restrict__ W2,
                                                const float* __restrict__ b2,
                                                const float* __restrict__ W3,
                                                const float* __restrict__ b3,
                                                float* __restrict__ logits) {
  int n = blockIdx.x, tid = threadIdx.x;
  __shared__ float xs[D], h1[D], h2[64];
  xs[tid] = x[n * D + tid];
  __syncthreads();
  float a = b1[tid];
  for (int kk = 0; kk < D; kk++) a += xs[kk] * W1[kk * D + tid];
  h1[tid] = fmaxf(a, 0.f);
  __syncthreads();
  if (tid < 64) {
    float a2 = b2[tid];
    for (int kk = 0; kk < D; kk++) a2 += h1[kk] * W2[kk * 64 + tid];
    h2[tid] = fmaxf(a2, 0.f);
  }
  __syncthreads();
  float p0 = 0.f, p1 = 0.f;
  if (tid < 64) { p0 = h2[tid] * W3[tid * 2]; p1 = h2[tid] * W3[tid * 2 + 1]; }
#pragma unroll
  for (int m = 1; m < 64; m <<= 1) { p0 += __shfl_xor(p0, m, 64); p1 += __shfl_xor(p1, m, 64); }
  if (tid == 0) {
    logits[n * 2] = p0 + b3[0];
    logits[n * 2 + 1] = p1 + b3[1];
  }
}

// ---------- value head (single block) ----------
__global__ __launch_bounds__(128) void k_value(const float* __restrict__ pooled,
                                               const float* __restrict__ W1,
                                               const float* __restrict__ b1,
                                               const float* __restrict__ W2,
                                               const float* __restrict__ b2,
                                               const float* __restrict__ W3,
                                               const float* __restrict__ b3,
                                               float* __restrict__ val) {
  int tid = threadIdx.x;
  __shared__ float ps[D], v1[D], v2[64];
  ps[tid] = pooled[tid] * (1.f / N_NODES);
  __syncthreads();
  float a = b1[tid];
  for (int kk = 0; kk < D; kk++) a += ps[kk] * W1[kk * D + tid];
  v1[tid] = fmaxf(a, 0.f);
  __syncthreads();
  if (tid < 64) {
    float a2 = b2[tid];
    for (int kk = 0; kk < D; kk++) a2 += v1[kk] * W2[kk * 64 + tid];
    v2[tid] = fmaxf(a2, 0.f);
  }
  __syncthreads();
  float p = (tid < 64) ? v2[tid] * W3[tid] : 0.f;
#pragma unroll
  for (int m = 1; m < 64; m <<= 1) p += __shfl_xor(p, m, 64);
  if (tid == 0) val[0] = p + b3[0];
}

extern "C" void kernel_launch(void* const* d_in, const int* in_sizes, int n_in,
                              void* d_out, int out_size, void* d_ws, size_t ws_size,
                              hipStream_t stream) {
  const float* nf   = (const float*)d_in[0];
  const int*   ei   = (const int*)d_in[1];
  const float* pe   = (const float*)d_in[2];
  const float* embW = (const float*)d_in[3];
  const float* embB = (const float*)d_in[4];
  const float* elng = (const float*)d_in[5];
  const float* elnb = (const float*)d_in[6];
  const float* gatW = (const float*)d_in[7];
  const float* aS   = (const float*)d_in[8];
  const float* aD   = (const float*)d_in[9];
  const float* gatB = (const float*)d_in[10];
  const float* lng  = (const float*)d_in[11];
  const float* lnb  = (const float*)d_in[12];
  const float* Wq   = (const float*)d_in[13];
  const float* Wk   = (const float*)d_in[14];
  const float* Wv   = (const float*)d_in[15];
  const float* Wo   = (const float*)d_in[16];
  const float* bq   = (const float*)d_in[17];
  const float* bk   = (const float*)d_in[18];
  const float* bv   = (const float*)d_in[19];
  const float* bo   = (const float*)d_in[20];
  const float* cag  = (const float*)d_in[21];
  const float* cab  = (const float*)d_in[22];
  const float* pW1  = (const float*)d_in[23];
  const float* pb1  = (const float*)d_in[24];
  const float* pW2  = (const float*)d_in[25];
  const float* pb2  = (const float*)d_in[26];
  const float* pW3  = (const float*)d_in[27];
  const float* pb3  = (const float*)d_in[28];
  const float* vW1  = (const float*)d_in[29];
  const float* vb1  = (const float*)d_in[30];
  const float* vW2  = (const float*)d_in[31];
  const float* vb2  = (const float*)d_in[32];
  const float* vW3  = (const float*)d_in[33];
  const float* vb3  = (const float*)d_in[34];

  // workspace layout: fp32 buffers, then bf16 buffers, then int CSR arrays
  float* fw = (float*)d_ws;
  float* x      = fw; fw += N_NODES * D;
  float* hbuf   = fw; fw += N_NODES * D;   // reused as xa after GAT layers
  float* a_s    = fw; fw += N_NODES * H;
  float* a_d    = fw; fw += N_NODES * H;
  float* pooled = fw; fw += 128;
  unsigned short* ub = (unsigned short*)fw;
  unsigned short* qbf = ub; ub += N_NODES * D;
  unsigned short* kbf = ub; ub += N_NODES * D;
  unsigned short* vtb = ub; ub += N_NODES * D;
  int* ib     = (int*)ub;
  int* cnt    = ib; ib += N_NODES;
  int* cur    = ib; ib += N_NODES;
  int* indptr = ib; ib += N_NODES + 16;
  int* sorted = ib;

  float* out    = (float*)d_out;
  float* logits = out;
  float* val    = out + NQ_ * 2;
  float* outx   = out + NQ_ * 2 + 1;

  const int* esrc = ei;
  const int* edst = ei + E_EDGES;

  hipLaunchKernelGGL(k_zero, dim3(24), dim3(256), 0, stream, cnt, cur, pooled);
  hipLaunchKernelGGL(k_hist, dim3(512), dim3(256), 0, stream, edst, cnt);
  hipLaunchKernelGGL(k_scan, dim3(1), dim3(256), 0, stream, cnt, indptr);
  hipLaunchKernelGGL(k_scatter, dim3(512), dim3(256), 0, stream, esrc, edst, indptr, cur, sorted);
  hipLaunchKernelGGL(k_embed, dim3(N_NODES), dim3(128), 0, stream, nf, embW, embB, elng, elnb, x);
  for (int l = 0; l < L_LAYERS; l++) {
    hipLaunchKernelGGL(k_gat_gemm, dim3(N_NODES / 8), dim3(128), 0, stream,
                       x, gatW + l * D * D, aS + l * D, aD + l * D, hbuf, a_s, a_d);
    hipLaunchKernelGGL(k_gat_agg, dim3(N_NODES), dim3(128), 0, stream,
                       hbuf, a_s, a_d, indptr, sorted, gatB + l * D, lng + l * D, lnb + l * D, x);
  }
  hipLaunchKernelGGL(k_qkv, dim3(N_NODES / 8), dim3(128), 0, stream,
                     x, pe, Wq, Wk, Wv, bq, bk, bv, qbf, kbf, vtb);
  // attention writes fp32 into hbuf (free after GAT layers)
  hipLaunchKernelGGL(k_attn_mfma, dim3(N_NODES / 32, H), dim3(128), 0, stream, qbf, kbf, vtb, hbuf);
  hipLaunchKernelGGL(k_ca, dim3(N_NODES / 8), dim3(128), 0, stream,
                     hbuf, Wo, bo, cag, cab, x, pooled, outx);
  hipLaunchKernelGGL(k_policy, dim3(NQ_), dim3(128), 0, stream,
                     x, pW1, pb1, pW2, pb2, pW3, pb3, logits);
  hipLaunchKernelGGL(k_value, dim3(1), dim3(128), 0, stream,
                     pooled, vW1, vb1, vW2, vb2, vW3, vb3, val);
}